// Round 17
// baseline (507.893 us; speedup 1.0000x reference)
//
#include <hip/hip_runtime.h>
#include <math.h>

typedef unsigned short ushort;
typedef __attribute__((ext_vector_type(8))) short bf16x8;
typedef __attribute__((ext_vector_type(4))) float f32x4;

#define MFMA16(a, b, c) __builtin_amdgcn_mfma_f32_16x16x32_bf16(a, b, c, 0, 0, 0)
#define GLOAD16(g, l)                                                   \
  __builtin_amdgcn_global_load_lds(                                     \
      (const __attribute__((address_space(1))) unsigned int*)(g),       \
      (__attribute__((address_space(3))) unsigned int*)(l), 16, 0, 0)

__device__ __forceinline__ ushort f2bf(float f) {
  unsigned u = __float_as_uint(f);
  u += 0x7FFFu + ((u >> 16) & 1u);  // RNE
  return (ushort)(u >> 16);
}
__device__ __forceinline__ float bf2f(ushort b) {
  return __uint_as_float(((unsigned)b) << 16);
}
__device__ __forceinline__ unsigned pk_bf16(float a, float b) {
  unsigned u;
  asm("v_cvt_pk_bf16_f32 %0, %1, %2" : "=v"(u) : "v"(a), "v"(b));
  return u;
}

__device__ __forceinline__ void bicubic_taps(int i, float* w, int* idx) {
  const float a = -0.75f;
  float src = ((float)i + 0.5f) * 0.0625f - 0.5f;
  float fi = floorf(src);
  int i0 = (int)fi;
  float t = src - fi;
  #pragma unroll
  for (int k = -1; k <= 2; ++k) {
    float d = fabsf(t - (float)k);
    float wv;
    if (d <= 1.0f)
      wv = ((a + 2.0f) * d - (a + 3.0f)) * d * d + 1.0f;
    else if (d < 2.0f)
      wv = a * (((d - 5.0f) * d + 8.0f) * d - 4.0f);
    else
      wv = 0.0f;
    int ic = i0 + k;
    ic = ic < 0 ? 0 : (ic > 63 ? 63 : ic);
    w[k + 1] = wv;
    idx[k + 1] = ic;
  }
}

// Device-scope grid barrier: release fence + arrive counter + bounded spin +
// acquire fence. Requires all 512 blocks co-resident (guaranteed: 50KB LDS,
// <=128 VGPR via launch_bounds -> 2 blocks/CU x 256 CUs). Counters zeroed by
// a captured hipMemsetAsync every call. Bounded spin -> no-hang failure mode.
__device__ __forceinline__ void gbar(unsigned* bar, int idx) {
  __syncthreads();
  if (threadIdx.x == 0) {
    __threadfence();
    unsigned v = atomicAdd(&bar[idx * 2 + 0], 1u);
    if (v == 511u) {
      atomicExch(&bar[idx * 2 + 1], 1u);
    } else {
      unsigned g = 0;
      while (atomicAdd(&bar[idx * 2 + 1], 0u) == 0u && g < 67108864u) {
        __builtin_amdgcn_s_sleep(16);
        ++g;
      }
    }
  }
  __syncthreads();
  __threadfence();
}

struct MegaArgs {
  const float* x;
  const float* q_w; const float* q_b;
  const float* k_w; const float* k_b;
  const float* v_w; const float* v_b;
  const float* o_w; const float* o_b;
  const float* dw_w; const float* dw_b;
  const float* off_w; const float* btab;
  ushort* Xh; ushort* Wq; ushort* Wk; ushort* Wv;
  ushort* Woh; ushort* Wol;
  float* samp; ushort* biasb;
  ushort* Qb; ushort* Kb; ushort* Vb;
  ushort* Ksb; ushort* Vtr; ushort* Aoh;
  float* out;
  unsigned* bar;
};

// ===========================================================================
// Mega-kernel: 512 blocks x 512 threads, 5 phases, 4 manual grid barriers.
// LDS pool 50048 B (max phase: offset net) -> 2 blocks/CU co-resident.
// ===========================================================================
__global__ __launch_bounds__(512, 4) void mega(MegaArgs A) {
  __shared__ float smem[12512];  // 50048 B, aliased per phase
  int blk = blockIdx.x;
  int tid = threadIdx.x;
  int lane = tid & 63;

  // ======================= PHASE 1: front-end prep ========================
  {
    // ---- A. offset network: 8 px per block, 512 channels=threads ----
    float* wT = smem;            // [16][516]
    float* hT = smem + 8256;     // [8][516]
    float* ofs = smem + 12384;   // [8][16]
    int x0 = (blk & 3) * 8;
    int y = (blk >> 2) & 31;
    int b = blk >> 7;

    for (int e = tid; e < 2048; e += 512) {
      int o = e >> 7, c4 = e & 127;
      *(float4*)&wT[o * 516 + c4 * 4] = *(const float4*)&A.off_w[o * 512 + c4 * 4];
    }
    {
      int c = tid;
      float dwv[25];
      #pragma unroll
      for (int k = 0; k < 25; ++k) dwv[k] = A.dw_w[(size_t)c * 25 + k];
      float cbv = A.dw_b[c];
      const float* xb = A.x + (size_t)b * 1024 * 512 + c;
      bool rv[5];
      #pragma unroll
      for (int r = 0; r < 5; ++r) {
        int yy = y - 2 + r;
        rv[r] = (yy >= 0 && yy < 32);
      }
      float win[5][5];
      #pragma unroll
      for (int j = 0; j < 4; ++j) {
        int xc = x0 - 2 + j;
        bool cvld = (xc >= 0 && xc < 32);
        #pragma unroll
        for (int r = 0; r < 5; ++r)
          win[r][j] = (rv[r] && cvld)
              ? xb[(size_t)((y - 2 + r) * 32 + xc) * 512] : 0.f;
      }
      #pragma unroll
      for (int i = 0; i < 8; ++i) {
        int xc = x0 + i + 2;
        bool cvld = (xc < 32);
        #pragma unroll
        for (int r = 0; r < 5; ++r)
          win[r][4] = (rv[r] && cvld)
              ? xb[(size_t)((y - 2 + r) * 32 + xc) * 512] : 0.f;
        float s = cbv;
        #pragma unroll
        for (int r = 0; r < 5; ++r)
          #pragma unroll
          for (int j = 0; j < 5; ++j) s += win[r][j] * dwv[r * 5 + j];
        hT[i * 516 + c] = 0.5f * s * (1.0f + erff(s * 0.70710678118654752f));
        #pragma unroll
        for (int r = 0; r < 5; ++r) {
          win[r][0] = win[r][1]; win[r][1] = win[r][2];
          win[r][2] = win[r][3]; win[r][3] = win[r][4];
        }
      }
    }
    __syncthreads();
    {
      // 1x1 matvec: 128 dots (8px x 16o), 4 threads per dot
      int dot = tid >> 2, part = tid & 3;
      int px = dot >> 4, o = dot & 15;
      float acc = 0.f;
      #pragma unroll 8
      for (int u = 0; u < 32; ++u) {
        int c4 = part * 32 + u;
        float4 hv = *(const float4*)&hT[px * 516 + c4 * 4];
        float4 wv = *(const float4*)&wT[o * 516 + c4 * 4];
        acc += hv.x * wv.x + hv.y * wv.y + hv.z * wv.z + hv.w * wv.w;
      }
      acc += __shfl_xor(acc, 1);
      acc += __shfl_xor(acc, 2);
      if (part == 0) ofs[px * 16 + o] = tanhf(acc) * 2.0f;
    }
    __syncthreads();
    if (tid < 64) {
      int px = tid >> 3, h = tid & 7;
      int n = y * 32 + x0 + px;
      float gx = -1.0f + 2.0f * (float)(x0 + px) / 31.0f;
      float gy = -1.0f + 2.0f * (float)y / 31.0f;
      float sx = fminf(fmaxf(gx + ofs[px * 16 + 2 * h], -1.0f), 1.0f);
      float sy = fminf(fmaxf(gy + ofs[px * 16 + 2 * h + 1], -1.0f), 1.0f);
      float2 pc;
      pc.x = (sx + 1.0f) * 16.0f - 0.5f;
      pc.y = (sy + 1.0f) * 16.0f - 0.5f;
      ((float2*)A.samp)[(size_t)(b * 8 + h) * 1024 + n] = pc;
    }
    __syncthreads();

    // ---- B. bias: 2 rows per block ----
    float* tab = smem;
    if (tid < 225) tab[tid] = A.btab[tid];
    __syncthreads();
    {
      int i = blk * 2 + (tid >> 8);
      float wA[4]; int iA[4];
      bicubic_taps(i, wA, iA);
      for (int j = (tid & 255); j < 1024; j += 256) {
        float wB[4]; int iB[4];
        bicubic_taps(j, wB, iB);
        float sum = 0.f;
        #pragma unroll
        for (int ka = 0; ka < 4; ++ka) {
          int pa = iA[ka];
          int py = pa >> 3, px = pa & 7;
          float wa = wA[ka];
          #pragma unroll
          for (int kb = 0; kb < 4; ++kb) {
            int qb = iB[kb];
            int qy = qb >> 3, qx = qb & 7;
            sum += wa * wB[kb] * tab[(py - qy + 7) * 15 + (px - qx + 7)];
          }
        }
        A.biasb[(size_t)i * 1024 + j] = f2bf(sum);
      }
    }

    // ---- C. x -> bf16 (1024 float4 per block) ----
    #pragma unroll
    for (int k = 0; k < 2; ++k) {
      int i = blk * 1024 + k * 512 + tid;
      float4 v = ((const float4*)A.x)[i];
      ushort4 h;
      h.x = f2bf(v.x); h.y = f2bf(v.y); h.z = f2bf(v.z); h.w = f2bf(v.w);
      ((ushort4*)A.Xh)[i] = h;
    }

    // ---- D. weights (512 float4 per block) ----
    {
      int idx = blk * 512 + tid;
      int grp = idx >> 16, i = idx & 65535;
      if (grp < 3) {
        const float* in = grp == 0 ? A.q_w : grp == 1 ? A.k_w : A.v_w;
        ushort* hi = grp == 0 ? A.Wq : grp == 1 ? A.Wk : A.Wv;
        float4 v = ((const float4*)in)[i];
        ushort4 h;
        h.x = f2bf(v.x); h.y = f2bf(v.y); h.z = f2bf(v.z); h.w = f2bf(v.w);
        ((ushort4*)hi)[i] = h;
      } else {
        float4 v = ((const float4*)A.o_w)[i];
        ushort4 h, l;
        h.x = f2bf(v.x); l.x = f2bf(v.x - bf2f(h.x));
        h.y = f2bf(v.y); l.y = f2bf(v.y - bf2f(h.y));
        h.z = f2bf(v.z); l.z = f2bf(v.z - bf2f(h.z));
        h.w = f2bf(v.w); l.w = f2bf(v.w - bf2f(h.w));
        ((ushort4*)A.Woh)[i] = h;
        ((ushort4*)A.Wol)[i] = l;
      }
    }
  }
  gbar(A.bar, 0);

  // ================= PHASE 2: fused QKV GEMM (128x128, 384 jobs) ==========
  if (blk < 384) {
    ushort* sA = (ushort*)smem;
    ushort* sB = sA + 8192;
    int which = blk / 128;
    int rem = blk - which * 128;
    int n0 = (rem & 3) * 128;
    int m0 = (rem >> 2) * 128;
    const ushort* W; const float* bb; ushort* Y; float scale;
    if (which == 0)      { W = A.Wq; bb = A.q_b; Y = A.Qb; scale = 0.125f; }
    else if (which == 1) { W = A.Wk; bb = A.k_b; Y = A.Kb; scale = 1.0f; }
    else                 { W = A.Wv; bb = A.v_b; Y = A.Vb; scale = 1.0f; }

    int w = tid >> 6;
    int wr = (w >> 2) * 64;
    int wc = (w & 3) * 32;
    int l8r = lane >> 3;
    int sll = ((lane & 7) ^ l8r) << 3;
    int l16 = lane & 15, lq = lane >> 4;

    f32x4 acc[4][2];
    f32x4 zero = {0.f, 0.f, 0.f, 0.f};
    #pragma unroll
    for (int m = 0; m < 4; ++m)
      #pragma unroll
      for (int n = 0; n < 2; ++n) acc[m][n] = zero;

    for (int kt = 0; kt < 8; ++kt) {
      int kk = kt * 64;
      __syncthreads();
      #pragma unroll
      for (int q = 0; q < 2; ++q) {
        int ci = w * 2 + q;
        GLOAD16(A.Xh + (size_t)(m0 + ci * 8 + l8r) * 512 + kk + sll, sA + ci * 512);
        GLOAD16(W + (size_t)(n0 + ci * 8 + l8r) * 512 + kk + sll, sB + ci * 512);
      }
      __syncthreads();
      #pragma unroll
      for (int ks = 0; ks < 2; ++ks) {
        int slot = ks * 4 + lq;
        bf16x8 a[4], bvv[2];
        #pragma unroll
        for (int m = 0; m < 4; ++m) {
          int r = wr + m * 16 + l16;
          a[m] = *(const bf16x8*)&sA[r * 64 + ((slot ^ (r & 7)) << 3)];
        }
        #pragma unroll
        for (int n = 0; n < 2; ++n) {
          int r = wc + n * 16 + l16;
          bvv[n] = *(const bf16x8*)&sB[r * 64 + ((slot ^ (r & 7)) << 3)];
        }
        #pragma unroll
        for (int m = 0; m < 4; ++m)
          #pragma unroll
          for (int n = 0; n < 2; ++n)
            acc[m][n] = MFMA16(a[m], bvv[n], acc[m][n]);
      }
    }
    #pragma unroll
    for (int n = 0; n < 2; ++n) {
      int col = n0 + wc + n * 16 + l16;
      float bv = bb[col];
      #pragma unroll
      for (int m = 0; m < 4; ++m) {
        #pragma unroll
        for (int j = 0; j < 4; ++j) {
          int row = m0 + wr + m * 16 + lq * 4 + j;
          Y[(size_t)row * 512 + col] = f2bf((acc[m][n][j] + bv) * scale);
        }
      }
    }
  }
  gbar(A.bar, 1);

  // ====================== PHASE 3: grid-sample =============================
  {
    ushort* sV = (ushort*)smem;  // [64][72]
    int bh = blk >> 4;
    int jb = blk & 15;
    int b = bh >> 3, h = bh & 7;
    int d = tid & 63;
    for (int p = 0; p < 8; ++p) {
      int jl = p * 8 + (tid >> 6);
      int j = jb * 64 + jl;
      float2 pc = ((const float2*)A.samp)[(size_t)bh * 1024 + j];
      float gx = pc.x, gy = pc.y;
      float x0 = floorf(gx), y0 = floorf(gy);
      float aK = 0.f, aV = 0.f;
      #pragma unroll
      for (int dy = 0; dy < 2; ++dy)
        #pragma unroll
        for (int dx = 0; dx < 2; ++dx) {
          float xi = x0 + (float)dx, yi = y0 + (float)dy;
          float wgt = (1.0f - fabsf(gx - xi)) * (1.0f - fabsf(gy - yi));
          if (xi >= 0.f && xi < 32.f && yi >= 0.f && yi < 32.f) {
            size_t base = ((size_t)b * 1024 + (int)yi * 32 + (int)xi) * 512 + h * 64 + d;
            aK += bf2f(A.Kb[base]) * wgt;
            aV += bf2f(A.Vb[base]) * wgt;
          }
        }
      A.Ksb[((size_t)bh * 1024 + j) * 64 + d] = f2bf(aK);
      sV[jl * 72 + d] = f2bf(aV);
    }
    __syncthreads();
    if (tid < 256) {
      int dd = tid >> 2, c4 = tid & 3;
      bf16x8 v0, v1;
      #pragma unroll
      for (int k = 0; k < 8; ++k) v0[k] = (short)sV[(c4 * 16 + k) * 72 + dd];
      #pragma unroll
      for (int k = 0; k < 8; ++k) v1[k] = (short)sV[(c4 * 16 + 8 + k) * 72 + dd];
      size_t o = ((size_t)bh * 64 + dd) * 1024 + jb * 64 + c4 * 16;
      *(bf16x8*)&A.Vtr[o] = v0;
      *(bf16x8*)&A.Vtr[o + 8] = v1;
    }
  }
  gbar(A.bar, 2);

  // ====================== PHASE 4: flash attention =========================
  {
    ushort* sK = (ushort*)smem;        // [2][2][2048] = 8192 ushorts
    ushort* sVt = sK + 8192;           // 8192 ushorts
    ushort* sP = sVt + 8192;           // 8 x 640 ushorts
    int w = tid >> 6;
    int qg = w & 3;
    int kvh = w >> 2;
    int l16 = lane & 15, lq = lane >> 4;
    int xcd = blk & 7;
    int rr = blk >> 3;
    int bh = ((rr & 3) << 3) + xcd;
    int i0 = (rr >> 2) * 64;
    int b = bh >> 3, h = bh & 7;

    bf16x8 qh[2];
    #pragma unroll
    for (int s = 0; s < 2; ++s)
      qh[s] = *(const bf16x8*)&A.Qb[((size_t)b * 1024 + i0 + qg * 16 + l16) * 512 +
                                    h * 64 + s * 32 + lq * 8];

    f32x4 oacc[4];
    f32x4 zero = {0.f, 0.f, 0.f, 0.f};
    #pragma unroll
    for (int n = 0; n < 4; ++n) oacc[n] = zero;
    float mq = -INFINITY, lsum = 0.f;

    ushort* myP = sP + w * 640;
    int krow = qg * 8 + (lane >> 3);
    int kslot = (lane & 7) ^ (krow & 7);
    int vrow = qg * 16 + (lane >> 2);
    int vslot = (lane & 3) ^ (vrow & 3);
    size_t kbase = ((size_t)bh * 1024 + kvh * 512 + krow) * 64 + kslot * 8;
    size_t vbase = ((size_t)bh * 64 + vrow) * 1024 + kvh * 512 + vslot * 8;
    ushort* dK0 = sK + (0 * 2 + kvh) * 2048 + qg * 8 * 64;
    ushort* dK1 = sK + (1 * 2 + kvh) * 2048 + qg * 8 * 64;
    ushort* dV0 = sVt + (0 * 2 + kvh) * 2048 + qg * 16 * 32;
    ushort* dV1 = sVt + (1 * 2 + kvh) * 2048 + qg * 16 * 32;
    const ushort* bprow = A.biasb + (size_t)(i0 + qg * 16 + l16) * 1024 + kvh * 512;

    GLOAD16(A.Ksb + kbase, dK0);
    GLOAD16(A.Vtr + vbase, dV0);
    ushort4 bias_c[2];
    #pragma unroll
    for (int n = 0; n < 2; ++n)
      bias_c[n] = *(const ushort4*)&bprow[n * 16 + lq * 4];
    __syncthreads();

    int cur = 0;
    for (int t = 0; t < 16; ++t) {
      if (t < 15) {
        size_t off = (size_t)(t + 1) * 32;
        GLOAD16(A.Ksb + kbase + off * 64, cur ? dK0 : dK1);
        GLOAD16(A.Vtr + vbase + off, cur ? dV0 : dV1);
      }
      f32x4 sacc[2];
      #pragma unroll
      for (int n = 0; n < 2; ++n) {
        sacc[n][0] = bf2f(bias_c[n].x);
        sacc[n][1] = bf2f(bias_c[n].y);
        sacc[n][2] = bf2f(bias_c[n].z);
        sacc[n][3] = bf2f(bias_c[n].w);
      }
      if (t < 15) {
        #pragma unroll
        for (int n = 0; n < 2; ++n)
          bias_c[n] = *(const ushort4*)&bprow[(t + 1) * 32 + n * 16 + lq * 4];
      }
      const ushort* k_t = sK + cur * 4096 + kvh * 2048;
      __builtin_amdgcn_s_setprio(1);
      #pragma unroll
      for (int ks = 0; ks < 2; ++ks) {
        int cslot = ((ks * 4 + lq) ^ (l16 & 7)) * 8;
        #pragma unroll
        for (int n = 0; n < 2; ++n) {
          bf16x8 aK = *(const bf16x8*)&k_t[(n * 16 + l16) * 64 + cslot];
          sacc[n] = MFMA16(aK, qh[ks], sacc[n]);
        }
      }
      __builtin_amdgcn_s_setprio(0);
      float mt = fmaxf(fmaxf(fmaxf(sacc[0][0], sacc[0][1]), fmaxf(sacc[0][2], sacc[0][3])),
                       fmaxf(fmaxf(sacc[1][0], sacc[1][1]), fmaxf(sacc[1][2], sacc[1][3])));
      mt = fmaxf(mt, __shfl_xor(mt, 16));
      mt = fmaxf(mt, __shfl_xor(mt, 32));
      if (!__all(mt <= mq + 8.0f)) {
        float mn = fmaxf(mq, mt);
        float sc = __expf(mq - mn);
        mq = mn;
        lsum *= sc;
        float scq[4];
        #pragma unroll
        for (int r = 0; r < 4; ++r) scq[r] = __shfl(sc, lq * 4 + r);
        #pragma unroll
        for (int n = 0; n < 4; ++n)
          #pragma unroll
          for (int r = 0; r < 4; ++r) oacc[n][r] *= scq[r];
      }
      float ts = 0.f;
      #pragma unroll
      for (int n = 0; n < 2; ++n) {
        float p0 = __expf(sacc[n][0] - mq);
        float p1 = __expf(sacc[n][1] - mq);
        float p2 = __expf(sacc[n][2] - mq);
        float p3 = __expf(sacc[n][3] - mq);
        ts += (p0 + p1) + (p2 + p3);
        uint2 u = make_uint2(pk_bf16(p0, p1), pk_bf16(p2, p3));
        *(uint2*)&myP[l16 * 40 + n * 16 + lq * 4] = u;
      }
      ts += __shfl_xor(ts, 16);
      ts += __shfl_xor(ts, 32);
      lsum += ts;
      bf16x8 pa = *(const bf16x8*)&myP[l16 * 40 + lq * 8];
      const ushort* vt_t = sVt + cur * 4096 + kvh * 2048;
      __builtin_amdgcn_s_setprio(1);
      #pragma unroll
      for (int n = 0; n < 4; ++n) {
        int row = n * 16 + l16;
        bf16x8 bv = *(const bf16x8*)&vt_t[row * 32 + ((lq ^ (row & 3)) * 8)];
        oacc[n] = MFMA16(pa, bv, oacc[n]);
      }
      __builtin_amdgcn_s_setprio(0);
      __syncthreads();
      cur ^= 1;
    }

    float* mO = (float*)sK;
    float* mML = (float*)sVt;
    if (w >= 4) {
      int base = ((w - 4) * 64 + lane) * 16;
      #pragma unroll
      for (int n = 0; n < 4; ++n)
        #pragma unroll
        for (int r = 0; r < 4; ++r) mO[base + n * 4 + r] = oacc[n][r];
      mML[((w - 4) * 64 + lane) * 2 + 0] = mq;
      mML[((w - 4) * 64 + lane) * 2 + 1] = lsum;
    }
    __syncthreads();
    if (w < 4) {
      float mB = mML[(w * 64 + lane) * 2 + 0];
      float lB = mML[(w * 64 + lane) * 2 + 1];
      float mS = fmaxf(mq, mB);
      float fA = __expf(mq - mS), fB = __expf(mB - mS);
      float linv = 1.0f / (lsum * fA + lB * fB);
      float cAv = fA * linv, cBv = fB * linv;
      float cA[4], cB[4];
      #pragma unroll
      for (int r = 0; r < 4; ++r) {
        cA[r] = __shfl(cAv, lq * 4 + r);
        cB[r] = __shfl(cBv, lq * 4 + r);
      }
      int base = (w * 64 + lane) * 16;
      #pragma unroll
      for (int r = 0; r < 4; ++r) {
        int qr = i0 + qg * 16 + lq * 4 + r;
        #pragma unroll
        for (int n = 0; n < 4; ++n) {
          float v = oacc[n][r] * cA[r] + mO[base + n * 4 + r] * cB[r];
          size_t o = ((size_t)b * 1024 + qr) * 512 + h * 64 + n * 16 + l16;
          A.Aoh[o] = f2bf(v);
        }
      }
    }
  }
  gbar(A.bar, 3);

  // ====================== PHASE 5: O-projection ============================
  {
    ushort* sA = (ushort*)smem;
    ushort* sWh = sA + 4096;
    ushort* sWl = sWh + 4096;
    int m0 = (blk >> 3) * 64, n0 = (blk & 7) * 64;
    int w = tid >> 6;
    int wr = (w >> 1) * 32;
    int wc = (w & 1) * 32;
    int l8r = lane >> 3;
    int sll = ((lane & 7) ^ l8r) << 3;
    int l16 = lane & 15, lq = lane >> 4;

    f32x4 acc[2][2];
    f32x4 zero = {0.f, 0.f, 0.f, 0.f};
    #pragma unroll
    for (int m = 0; m < 2; ++m)
      #pragma unroll
      for (int n = 0; n < 2; ++n) acc[m][n] = zero;

    for (int kt = 0; kt < 8; ++kt) {
      int kk = kt * 64;
      __syncthreads();
      if (tid < 256) {
        #pragma unroll
        for (int q = 0; q < 2; ++q) {
          int ci = w * 2 + q;
          size_t ga = (size_t)(m0 + ci * 8 + l8r) * 512 + kk + sll;
          GLOAD16(A.Aoh + ga, sA + ci * 512);
          size_t gw = (size_t)(n0 + ci * 8 + l8r) * 512 + kk + sll;
          GLOAD16(A.Woh + gw, sWh + ci * 512);
          GLOAD16(A.Wol + gw, sWl + ci * 512);
        }
      }
      __syncthreads();
      if (tid < 256) {
        #pragma unroll
        for (int ks = 0; ks < 2; ++ks) {
          int slot = ks * 4 + lq;
          bf16x8 a[2], bh[2], bl[2];
          #pragma unroll
          for (int m = 0; m < 2; ++m) {
            int r = wr + m * 16 + l16;
            a[m] = *(const bf16x8*)&sA[r * 64 + ((slot ^ (r & 7)) << 3)];
          }
          #pragma unroll
          for (int n = 0; n < 2; ++n) {
            int r = wc + n * 16 + l16;
            int ph = (slot ^ (r & 7)) << 3;
            bh[n] = *(const bf16x8*)&sWh[r * 64 + ph];
            bl[n] = *(const bf16x8*)&sWl[r * 64 + ph];
          }
          #pragma unroll
          for (int m = 0; m < 2; ++m)
            #pragma unroll
            for (int n = 0; n < 2; ++n) {
              acc[m][n] = MFMA16(a[m], bh[n], acc[m][n]);
              acc[m][n] = MFMA16(a[m], bl[n], acc[m][n]);
            }
        }
      }
    }
    if (tid < 256) {
      #pragma unroll
      for (int n = 0; n < 2; ++n) {
        int col = n0 + wc + n * 16 + l16;
        float bv = A.o_b[col];
        #pragma unroll
        for (int m = 0; m < 2; ++m) {
          #pragma unroll
          for (int j = 0; j < 4; ++j) {
            int row = m0 + wr + m * 16 + lq * 4 + j;
            A.out[(size_t)row * 512 + col] = acc[m][n][j] + bv;
          }
        }
      }
    }
  }
}

// ---------------------------------------------------------------------------
extern "C" void kernel_launch(void* const* d_in, const int* in_sizes, int n_in,
                              void* d_out, int out_size, void* d_ws, size_t ws_size,
                              hipStream_t stream) {
  float* ws = (float*)d_ws;
  const size_t SZ = (size_t)4 * 1024 * 512;  // 2M elements
  float* samp = ws;                          // 65536 floats

  ushort* u = (ushort*)(samp + 65536);
  ushort* Xh    = u;               // 2M ushorts each
  ushort* Qb    = Xh + SZ;
  ushort* Kb    = Qb + SZ;
  ushort* Vb    = Kb + SZ;
  ushort* Ksb   = Vb + SZ;
  ushort* Vtr   = Ksb + SZ;
  ushort* Aoh   = Vtr + SZ;
  ushort* biasb = Aoh + SZ;        // 1M ushorts (2 MB)
  ushort* Wq    = biasb + 1048576; // 256K ushorts each
  ushort* Wk    = Wq + 262144;
  ushort* Wv    = Wk + 262144;
  ushort* Woh   = Wv + 262144;
  ushort* Wol   = Woh + 262144;
  unsigned* bar = (unsigned*)(Wol + 262144);  // 8 unsigneds

  // zero barrier counters (stream-ordered; captured into the graph)
  hipMemsetAsync(bar, 0, 32, stream);

  MegaArgs a;
  a.x = (const float*)d_in[0];
  a.q_w = (const float*)d_in[1]; a.q_b = (const float*)d_in[2];
  a.k_w = (const float*)d_in[3]; a.k_b = (const float*)d_in[4];
  a.v_w = (const float*)d_in[5]; a.v_b = (const float*)d_in[6];
  a.o_w = (const float*)d_in[7]; a.o_b = (const float*)d_in[8];
  a.dw_w = (const float*)d_in[9]; a.dw_b = (const float*)d_in[10];
  a.off_w = (const float*)d_in[11]; a.btab = (const float*)d_in[12];
  a.Xh = Xh; a.Wq = Wq; a.Wk = Wk; a.Wv = Wv; a.Woh = Woh; a.Wol = Wol;
  a.samp = samp; a.biasb = biasb;
  a.Qb = Qb; a.Kb = Kb; a.Vb = Vb; a.Ksb = Ksb; a.Vtr = Vtr; a.Aoh = Aoh;
  a.out = (float*)d_out;
  a.bar = bar;

  mega<<<512, 512, 0, stream>>>(a);
}

// Round 18
// 101.690 us; speedup vs baseline: 4.9945x; 4.9945x over previous
//
#include <hip/hip_runtime.h>
#include <math.h>

typedef unsigned short ushort;
typedef __attribute__((ext_vector_type(8))) short bf16x8;
typedef __attribute__((ext_vector_type(4))) float f32x4;

#define MFMA16(a, b, c) __builtin_amdgcn_mfma_f32_16x16x32_bf16(a, b, c, 0, 0, 0)
#define GLOAD16(g, l)                                                   \
  __builtin_amdgcn_global_load_lds(                                     \
      (const __attribute__((address_space(1))) unsigned int*)(g),       \
      (__attribute__((address_space(3))) unsigned int*)(l), 16, 0, 0)

__device__ __forceinline__ ushort f2bf(float f) {
  unsigned u = __float_as_uint(f);
  u += 0x7FFFu + ((u >> 16) & 1u);  // RNE
  return (ushort)(u >> 16);
}
__device__ __forceinline__ float bf2f(ushort b) {
  return __uint_as_float(((unsigned)b) << 16);
}
__device__ __forceinline__ unsigned pk_bf16(float a, float b) {
  unsigned u;
  asm("v_cvt_pk_bf16_f32 %0, %1, %2" : "=v"(u) : "v"(a), "v"(b));
  return u;
}

__device__ __forceinline__ void bicubic_taps(int i, float* w, int* idx) {
  const float a = -0.75f;
  float src = ((float)i + 0.5f) * 0.0625f - 0.5f;
  float fi = floorf(src);
  int i0 = (int)fi;
  float t = src - fi;
  #pragma unroll
  for (int k = -1; k <= 2; ++k) {
    float d = fabsf(t - (float)k);
    float wv;
    if (d <= 1.0f)
      wv = ((a + 2.0f) * d - (a + 3.0f)) * d * d + 1.0f;
    else if (d < 2.0f)
      wv = a * (((d - 5.0f) * d + 8.0f) * d - 4.0f);
    else
      wv = 0.0f;
    int ic = i0 + k;
    ic = ic < 0 ? 0 : (ic > 63 ? 63 : ic);
    w[k + 1] = wv;
    idx[k + 1] = ic;
  }
}

// ---------------------------------------------------------------------------
// stage1: fused independent front-end, longest-job-first block order.
//   blocks [0,512)     : offset network (8 px per block)
//   blocks [512,1536)  : bias (bicubic rel-pos bias -> bf16)
//   blocks [1536,3584) : x -> bf16
//   blocks [3584,4608) : q/k/v weights -> bf16 hi; o_w -> hi/lo
// ---------------------------------------------------------------------------
__global__ __launch_bounds__(256) void stage1(
    const float* __restrict__ x, const float* __restrict__ q_w,
    const float* __restrict__ k_w, const float* __restrict__ v_w,
    const float* __restrict__ o_w, const float* __restrict__ dw_w,
    const float* __restrict__ dw_b, const float* __restrict__ off_w,
    const float* __restrict__ btab, ushort* __restrict__ Xh,
    ushort* __restrict__ Wq, ushort* __restrict__ Wk, ushort* __restrict__ Wv,
    ushort* __restrict__ Woh, ushort* __restrict__ Wol,
    float* __restrict__ samp, ushort* __restrict__ biasb) {
  __shared__ float smem[16768];
  int blk = blockIdx.x;
  int tid = threadIdx.x;

  if (blk < 512) {
    // ---- offset-network branch: 8 pixels per block ----
    float* wT = smem;            // [16][516]
    float* hT = smem + 8256;     // [8][516]
    float* ofs = smem + 12384;   // [8][16]
    int ob = blk;
    int x0 = (ob & 3) * 8;
    int y = (ob >> 2) & 31;
    int b = ob >> 7;

    for (int e = tid; e < 2048; e += 256) {
      int o = e >> 7, c4 = e & 127;
      *(float4*)&wT[o * 516 + c4 * 4] = *(const float4*)&off_w[o * 512 + c4 * 4];
    }

    int c = tid * 2;
    float2 dwv[25];
    #pragma unroll
    for (int k = 0; k < 25; ++k) {
      dwv[k].x = dw_w[(size_t)c * 25 + k];
      dwv[k].y = dw_w[(size_t)(c + 1) * 25 + k];
    }
    float2 cb = *(const float2*)&dw_b[c];

    const float* xb = x + (size_t)b * 1024 * 512 + c;
    bool rv[5];
    #pragma unroll
    for (int r = 0; r < 5; ++r) {
      int yy = y - 2 + r;
      rv[r] = (yy >= 0 && yy < 32);
    }
    float2 win[5][5];
    #pragma unroll
    for (int j = 0; j < 4; ++j) {
      int xc = x0 - 2 + j;
      bool cvld = (xc >= 0 && xc < 32);
      #pragma unroll
      for (int r = 0; r < 5; ++r) {
        win[r][j] = (rv[r] && cvld)
            ? *(const float2*)&xb[(size_t)((y - 2 + r) * 32 + xc) * 512]
            : make_float2(0.f, 0.f);
      }
    }
    #pragma unroll
    for (int i = 0; i < 8; ++i) {
      int xc = x0 + i + 2;
      bool cvld = (xc < 32);
      #pragma unroll
      for (int r = 0; r < 5; ++r) {
        win[r][4] = (rv[r] && cvld)
            ? *(const float2*)&xb[(size_t)((y - 2 + r) * 32 + xc) * 512]
            : make_float2(0.f, 0.f);
      }
      float sx = cb.x, sy = cb.y;
      #pragma unroll
      for (int r = 0; r < 5; ++r)
        #pragma unroll
        for (int j = 0; j < 5; ++j) {
          sx += win[r][j].x * dwv[r * 5 + j].x;
          sy += win[r][j].y * dwv[r * 5 + j].y;
        }
      float g0 = 0.5f * sx * (1.0f + erff(sx * 0.70710678118654752f));
      float g1 = 0.5f * sy * (1.0f + erff(sy * 0.70710678118654752f));
      *(float2*)&hT[i * 516 + c] = make_float2(g0, g1);
      #pragma unroll
      for (int r = 0; r < 5; ++r) {
        win[r][0] = win[r][1]; win[r][1] = win[r][2];
        win[r][2] = win[r][3]; win[r][3] = win[r][4];
      }
    }
    __syncthreads();
    if (tid < 128) {
      int o = tid & 15, px = tid >> 4;  // px 0..7
      float acc = 0.f;
      #pragma unroll 4
      for (int c4 = 0; c4 < 128; ++c4) {
        float4 hv = *(const float4*)&hT[px * 516 + c4 * 4];
        float4 wv = *(const float4*)&wT[o * 516 + c4 * 4];
        acc += hv.x * wv.x + hv.y * wv.y + hv.z * wv.z + hv.w * wv.w;
      }
      ofs[px * 16 + o] = tanhf(acc) * 2.0f;
    }
    __syncthreads();
    if (tid < 64) {
      int px = tid >> 3, h = tid & 7;
      int n = y * 32 + x0 + px;
      float gx = -1.0f + 2.0f * (float)(x0 + px) / 31.0f;
      float gy = -1.0f + 2.0f * (float)y / 31.0f;
      float sx = fminf(fmaxf(gx + ofs[px * 16 + 2 * h], -1.0f), 1.0f);
      float sy = fminf(fmaxf(gy + ofs[px * 16 + 2 * h + 1], -1.0f), 1.0f);
      float2 pc;
      pc.x = (sx + 1.0f) * 16.0f - 0.5f;
      pc.y = (sy + 1.0f) * 16.0f - 0.5f;
      ((float2*)samp)[(size_t)(b * 8 + h) * 1024 + n] = pc;
    }
  } else if (blk < 1536) {
    // ---- bias branch ----
    float* tab = smem;
    int i = blk - 512;
    if (tid < 225) tab[tid] = btab[tid];
    __syncthreads();
    float wA[4]; int iA[4];
    bicubic_taps(i, wA, iA);
    for (int j = tid; j < 1024; j += 256) {
      float wB[4]; int iB[4];
      bicubic_taps(j, wB, iB);
      float sum = 0.f;
      #pragma unroll
      for (int ka = 0; ka < 4; ++ka) {
        int pa = iA[ka];
        int py = pa >> 3, px = pa & 7;
        float wa = wA[ka];
        #pragma unroll
        for (int kb = 0; kb < 4; ++kb) {
          int qb = iB[kb];
          int qy = qb >> 3, qx = qb & 7;
          sum += wa * wB[kb] * tab[(py - qy + 7) * 15 + (px - qx + 7)];
        }
      }
      biasb[(size_t)i * 1024 + j] = f2bf(sum);
    }
  } else if (blk < 3584) {
    // ---- x -> bf16 ----
    int i = (blk - 1536) * 256 + tid;
    float4 v = ((const float4*)x)[i];
    ushort4 h;
    h.x = f2bf(v.x); h.y = f2bf(v.y); h.z = f2bf(v.z); h.w = f2bf(v.w);
    ((ushort4*)Xh)[i] = h;
  } else {
    // ---- weights ----
    int blk2 = blk - 3584;
    int grp = blk2 >> 8;
    int i = (blk2 & 255) * 256 + tid;
    if (grp < 3) {
      const float* in = grp == 0 ? q_w : grp == 1 ? k_w : v_w;
      ushort* hi = grp == 0 ? Wq : grp == 1 ? Wk : Wv;
      float4 v = ((const float4*)in)[i];
      ushort4 h;
      h.x = f2bf(v.x); h.y = f2bf(v.y); h.z = f2bf(v.z); h.w = f2bf(v.w);
      ((ushort4*)hi)[i] = h;
    } else {
      float4 v = ((const float4*)o_w)[i];
      ushort4 h, l;
      h.x = f2bf(v.x); l.x = f2bf(v.x - bf2f(h.x));
      h.y = f2bf(v.y); l.y = f2bf(v.y - bf2f(h.y));
      h.z = f2bf(v.z); l.z = f2bf(v.z - bf2f(h.z));
      h.w = f2bf(v.w); l.w = f2bf(v.w - bf2f(h.w));
      ((ushort4*)Woh)[i] = h;
      ((ushort4*)Wol)[i] = l;
    }
  }
}

// ---------------------------------------------------------------------------
// Fused QKV GEMM (proven 64-wide version): 128x64 tile, 256 thr.
// grid (24, 32): blockIdx.x = which*8 + nb.
// ---------------------------------------------------------------------------
__global__ __launch_bounds__(256) void gemm_qkv(
    const ushort* __restrict__ X, const ushort* __restrict__ Wq,
    const ushort* __restrict__ Wk, const ushort* __restrict__ Wv,
    const float* __restrict__ b0, const float* __restrict__ b1,
    const float* __restrict__ b2, ushort* __restrict__ Qo,
    ushort* __restrict__ Ko, ushort* __restrict__ Vo) {
  __shared__ ushort lds[12288];
  ushort* sA = lds;
  ushort* sB = lds + 8192;
  int which = blockIdx.x >> 3;
  int n0 = (blockIdx.x & 7) * 64;
  int m0 = blockIdx.y * 128;
  const ushort* W; const float* bb; ushort* Y; float scale;
  if (which == 0)      { W = Wq; bb = b0; Y = Qo; scale = 0.125f; }
  else if (which == 1) { W = Wk; bb = b1; Y = Ko; scale = 1.0f; }
  else                 { W = Wv; bb = b2; Y = Vo; scale = 1.0f; }

  int tid = threadIdx.x;
  int lane = tid & 63;
  int w = tid >> 6;
  int wr = (w >> 1) * 64;
  int wc = (w & 1) * 32;
  int l8r = lane >> 3;
  int sll = ((lane & 7) ^ l8r) << 3;
  int l16 = lane & 15, lq = lane >> 4;

  f32x4 acc[4][2];
  f32x4 zero = {0.f, 0.f, 0.f, 0.f};
  #pragma unroll
  for (int m = 0; m < 4; ++m)
    #pragma unroll
    for (int n = 0; n < 2; ++n) acc[m][n] = zero;

  for (int kt = 0; kt < 8; ++kt) {
    int kk = kt * 64;
    __syncthreads();
    #pragma unroll
    for (int q = 0; q < 4; ++q) {
      int ci = w * 4 + q;
      GLOAD16(X + (size_t)(m0 + ci * 8 + l8r) * 512 + kk + sll, sA + ci * 512);
    }
    #pragma unroll
    for (int q = 0; q < 2; ++q) {
      int ci = w * 2 + q;
      GLOAD16(W + (size_t)(n0 + ci * 8 + l8r) * 512 + kk + sll, sB + ci * 512);
    }
    __syncthreads();
    #pragma unroll
    for (int ks = 0; ks < 2; ++ks) {
      int slot = ks * 4 + lq;
      bf16x8 a[4], bvv[2];
      #pragma unroll
      for (int m = 0; m < 4; ++m) {
        int r = wr + m * 16 + l16;
        a[m] = *(const bf16x8*)&sA[r * 64 + ((slot ^ (r & 7)) << 3)];
      }
      #pragma unroll
      for (int n = 0; n < 2; ++n) {
        int r = wc + n * 16 + l16;
        bvv[n] = *(const bf16x8*)&sB[r * 64 + ((slot ^ (r & 7)) << 3)];
      }
      #pragma unroll
      for (int m = 0; m < 4; ++m)
        #pragma unroll
        for (int n = 0; n < 2; ++n)
          acc[m][n] = MFMA16(a[m], bvv[n], acc[m][n]);
    }
  }
  #pragma unroll
  for (int n = 0; n < 2; ++n) {
    int col = n0 + wc + n * 16 + l16;
    float bv = bb[col];
    #pragma unroll
    for (int m = 0; m < 4; ++m) {
      #pragma unroll
      for (int j = 0; j < 4; ++j) {
        int row = m0 + wr + m * 16 + lq * 4 + j;
        Y[(size_t)row * 512 + col] = f2bf((acc[m][n][j] + bv) * scale);
      }
    }
  }
}

// ---------------------------------------------------------------------------
// O-proj GEMM: Y = A_bf16 @ (Wh+Wl)^T + b, fp32 out, 2-pass.
// ---------------------------------------------------------------------------
__global__ __launch_bounds__(256) void gemm_o(
    const ushort* __restrict__ A, const ushort* __restrict__ Wh,
    const ushort* __restrict__ Wl, const float* __restrict__ bias,
    float* __restrict__ Y) {
  __shared__ ushort sA[4096];
  __shared__ ushort sWh[4096];
  __shared__ ushort sWl[4096];
  int m0 = blockIdx.y * 64, n0 = blockIdx.x * 64;
  int tid = threadIdx.x;
  int lane = tid & 63;
  int w = tid >> 6;
  int wr = (w >> 1) * 32;
  int wc = (w & 1) * 32;
  int l8r = lane >> 3;
  int sll = ((lane & 7) ^ l8r) << 3;
  int l16 = lane & 15, lq = lane >> 4;

  f32x4 acc[2][2];
  f32x4 zero = {0.f, 0.f, 0.f, 0.f};
  #pragma unroll
  for (int m = 0; m < 2; ++m)
    #pragma unroll
    for (int n = 0; n < 2; ++n) acc[m][n] = zero;

  for (int kt = 0; kt < 8; ++kt) {
    int kk = kt * 64;
    __syncthreads();
    #pragma unroll
    for (int q = 0; q < 2; ++q) {
      int ci = w * 2 + q;
      size_t ga = (size_t)(m0 + ci * 8 + l8r) * 512 + kk + sll;
      GLOAD16(A + ga, sA + ci * 512);
      size_t gw = (size_t)(n0 + ci * 8 + l8r) * 512 + kk + sll;
      GLOAD16(Wh + gw, sWh + ci * 512);
      GLOAD16(Wl + gw, sWl + ci * 512);
    }
    __syncthreads();
    #pragma unroll
    for (int ks = 0; ks < 2; ++ks) {
      int slot = ks * 4 + lq;
      bf16x8 a[2], bh[2], bl[2];
      #pragma unroll
      for (int m = 0; m < 2; ++m) {
        int r = wr + m * 16 + l16;
        a[m] = *(const bf16x8*)&sA[r * 64 + ((slot ^ (r & 7)) << 3)];
      }
      #pragma unroll
      for (int n = 0; n < 2; ++n) {
        int r = wc + n * 16 + l16;
        int ph = (slot ^ (r & 7)) << 3;
        bh[n] = *(const bf16x8*)&sWh[r * 64 + ph];
        bl[n] = *(const bf16x8*)&sWl[r * 64 + ph];
      }
      #pragma unroll
      for (int m = 0; m < 2; ++m)
        #pragma unroll
        for (int n = 0; n < 2; ++n) {
          acc[m][n] = MFMA16(a[m], bh[n], acc[m][n]);
          acc[m][n] = MFMA16(a[m], bl[n], acc[m][n]);
        }
    }
  }
  #pragma unroll
  for (int n = 0; n < 2; ++n) {
    int col = n0 + wc + n * 16 + l16;
    float bv = bias[col];
    #pragma unroll
    for (int m = 0; m < 2; ++m) {
      #pragma unroll
      for (int j = 0; j < 4; ++j) {
        int row = m0 + wr + m * 16 + lq * 4 + j;
        Y[(size_t)row * 512 + col] = acc[m][n][j] + bv;
      }
    }
  }
}

// ---------------------------------------------------------------------------
// Bilinear grid-sample of bf16 K,V -> Ks [bh][1024][64], Vt [bh][64][1024].
// ---------------------------------------------------------------------------
__global__ __launch_bounds__(256) void grid_sample(
    const ushort* __restrict__ K, const ushort* __restrict__ V,
    const float* __restrict__ samp, ushort* __restrict__ Ks,
    ushort* __restrict__ Vt) {
  __shared__ ushort sV[64][72];
  int bh = blockIdx.y;
  int b = bh >> 3, h = bh & 7;
  int jb = blockIdx.x;
  int d = threadIdx.x & 63;
  for (int p = 0; p < 16; ++p) {
    int jl = p * 4 + (threadIdx.x >> 6);
    int j = jb * 64 + jl;
    float2 pc = ((const float2*)samp)[(size_t)bh * 1024 + j];
    float gx = pc.x, gy = pc.y;
    float x0 = floorf(gx), y0 = floorf(gy);
    float aK = 0.f, aV = 0.f;
    #pragma unroll
    for (int dy = 0; dy < 2; ++dy)
      #pragma unroll
      for (int dx = 0; dx < 2; ++dx) {
        float xi = x0 + (float)dx, yi = y0 + (float)dy;
        float wgt = (1.0f - fabsf(gx - xi)) * (1.0f - fabsf(gy - yi));
        if (xi >= 0.f && xi < 32.f && yi >= 0.f && yi < 32.f) {
          size_t base = ((size_t)b * 1024 + (int)yi * 32 + (int)xi) * 512 + h * 64 + d;
          aK += bf2f(K[base]) * wgt;
          aV += bf2f(V[base]) * wgt;
        }
      }
    Ks[((size_t)bh * 1024 + j) * 64 + d] = f2bf(aK);
    sV[jl][d] = f2bf(aV);
  }
  __syncthreads();
  int dd = threadIdx.x >> 2, c4 = threadIdx.x & 3;
  bf16x8 v0, v1;
  #pragma unroll
  for (int k = 0; k < 8; ++k) v0[k] = (short)sV[c4 * 16 + k][dd];
  #pragma unroll
  for (int k = 0; k < 8; ++k) v1[k] = (short)sV[c4 * 16 + 8 + k][dd];
  size_t o = ((size_t)bh * 64 + dd) * 1024 + jb * 64 + c4 * 16;
  *(bf16x8*)&Vt[o] = v0;
  *(bf16x8*)&Vt[o + 8] = v1;
}

// ---------------------------------------------------------------------------
// MFMA flash attention (proven version): LDS double-buffered K/V via
// global_load_lds, one barrier/iter, swapped QK^T, defer-max, setprio.
// 8 waves (4 qg x 2 kvh), flash-merge at end.
// ---------------------------------------------------------------------------
__global__ __launch_bounds__(512, 6) void attn_mfma(
    const ushort* __restrict__ Qh, const ushort* __restrict__ Ks,
    const ushort* __restrict__ Vt, const ushort* __restrict__ bias,
    ushort* __restrict__ Oh) {
  __shared__ ushort sK[2][2][2048];   // [buf][half][32 keys x 64]
  __shared__ ushort sVt[2][2][2048];  // [buf][half][64 d x 32 keys]
  __shared__ ushort sP[8][640];       // per-wave [16 q][40]

  int tid = threadIdx.x;
  int lane = tid & 63;
  int w = tid >> 6;
  int qg = w & 3;
  int kvh = w >> 2;
  int l16 = lane & 15, lq = lane >> 4;
  int blk = blockIdx.x;
  int xcd = blk & 7;
  int rr = blk >> 3;
  int bh = ((rr & 3) << 3) + xcd;
  int i0 = (rr >> 2) * 64;
  int b = bh >> 3, h = bh & 7;

  bf16x8 qh[2];
  #pragma unroll
  for (int s = 0; s < 2; ++s)
    qh[s] = *(const bf16x8*)&Qh[((size_t)b * 1024 + i0 + qg * 16 + l16) * 512 +
                                h * 64 + s * 32 + lq * 8];

  f32x4 oacc[4];
  f32x4 zero = {0.f, 0.f, 0.f, 0.f};
  #pragma unroll
  for (int n = 0; n < 4; ++n) oacc[n] = zero;
  float mq = -INFINITY, lsum = 0.f;

  ushort* myP = sP[w];
  int krow = qg * 8 + (lane >> 3);
  int kslot = (lane & 7) ^ (krow & 7);
  int vrow = qg * 16 + (lane >> 2);
  int vslot = (lane & 3) ^ (vrow & 3);
  size_t kbase = ((size_t)bh * 1024 + kvh * 512 + krow) * 64 + kslot * 8;
  size_t vbase = ((size_t)bh * 64 + vrow) * 1024 + kvh * 512 + vslot * 8;
  ushort* dK0 = &sK[0][kvh][qg * 8 * 64];  ushort* dK1 = &sK[1][kvh][qg * 8 * 64];
  ushort* dV0 = &sVt[0][kvh][qg * 16 * 32]; ushort* dV1 = &sVt[1][kvh][qg * 16 * 32];
  const ushort* bprow = bias + (size_t)(i0 + qg * 16 + l16) * 1024 + kvh * 512;

  GLOAD16(Ks + kbase, dK0);
  GLOAD16(Vt + vbase, dV0);
  ushort4 bias_c[2];
  #pragma unroll
  for (int n = 0; n < 2; ++n)
    bias_c[n] = *(const ushort4*)&bprow[n * 16 + lq * 4];
  __syncthreads();

  int cur = 0;
  for (int t = 0; t < 16; ++t) {
    if (t < 15) {
      size_t off = (size_t)(t + 1) * 32;
      GLOAD16(Ks + kbase + off * 64, cur ? dK0 : dK1);
      GLOAD16(Vt + vbase + off, cur ? dV0 : dV1);
    }
    f32x4 sacc[2];
    #pragma unroll
    for (int n = 0; n < 2; ++n) {
      sacc[n][0] = bf2f(bias_c[n].x);
      sacc[n][1] = bf2f(bias_c[n].y);
      sacc[n][2] = bf2f(bias_c[n].z);
      sacc[n][3] = bf2f(bias_c[n].w);
    }
    if (t < 15) {
      #pragma unroll
      for (int n = 0; n < 2; ++n)
        bias_c[n] = *(const ushort4*)&bprow[(t + 1) * 32 + n * 16 + lq * 4];
    }
    const ushort* k_t = sK[cur][kvh];
    __builtin_amdgcn_s_setprio(1);
    #pragma unroll
    for (int ks = 0; ks < 2; ++ks) {
      int cslot = ((ks * 4 + lq) ^ (l16 & 7)) * 8;
      #pragma unroll
      for (int n = 0; n < 2; ++n) {
        bf16x8 aK = *(const bf16x8*)&k_t[(n * 16 + l16) * 64 + cslot];
        sacc[n] = MFMA16(aK, qh[ks], sacc[n]);
      }
    }
    __builtin_amdgcn_s_setprio(0);
    float mt = fmaxf(fmaxf(fmaxf(sacc[0][0], sacc[0][1]), fmaxf(sacc[0][2], sacc[0][3])),
                     fmaxf(fmaxf(sacc[1][0], sacc[1][1]), fmaxf(sacc[1][2], sacc[1][3])));
    mt = fmaxf(mt, __shfl_xor(mt, 16));
    mt = fmaxf(mt, __shfl_xor(mt, 32));
    if (!__all(mt <= mq + 8.0f)) {
      float mn = fmaxf(mq, mt);
      float sc = __expf(mq - mn);
      mq = mn;
      lsum *= sc;
      float scq[4];
      #pragma unroll
      for (int r = 0; r < 4; ++r) scq[r] = __shfl(sc, lq * 4 + r);
      #pragma unroll
      for (int n = 0; n < 4; ++n)
        #pragma unroll
        for (int r = 0; r < 4; ++r) oacc[n][r] *= scq[r];
    }
    float ts = 0.f;
    #pragma unroll
    for (int n = 0; n < 2; ++n) {
      float p0 = __expf(sacc[n][0] - mq);
      float p1 = __expf(sacc[n][1] - mq);
      float p2 = __expf(sacc[n][2] - mq);
      float p3 = __expf(sacc[n][3] - mq);
      ts += (p0 + p1) + (p2 + p3);
      uint2 u = make_uint2(pk_bf16(p0, p1), pk_bf16(p2, p3));
      *(uint2*)&myP[l16 * 40 + n * 16 + lq * 4] = u;
    }
    ts += __shfl_xor(ts, 16);
    ts += __shfl_xor(ts, 32);
    lsum += ts;
    bf16x8 pa = *(const bf16x8*)&myP[l16 * 40 + lq * 8];
    const ushort* vt_t = sVt[cur][kvh];
    __builtin_amdgcn_s_setprio(1);
    #pragma unroll
    for (int n = 0; n < 4; ++n) {
      int row = n * 16 + l16;
      bf16x8 bv = *(const bf16x8*)&vt_t[row * 32 + ((lq ^ (row & 3)) * 8)];
      oacc[n] = MFMA16(pa, bv, oacc[n]);
    }
    __builtin_amdgcn_s_setprio(0);
    __syncthreads();
    cur ^= 1;
  }

  float* mO = (float*)sK;
  float* mML = (float*)sVt;
  if (w >= 4) {
    int base = ((w - 4) * 64 + lane) * 16;
    #pragma unroll
    for (int n = 0; n < 4; ++n)
      #pragma unroll
      for (int r = 0; r < 4; ++r) mO[base + n * 4 + r] = oacc[n][r];
    mML[((w - 4) * 64 + lane) * 2 + 0] = mq;
    mML[((w - 4) * 64 + lane) * 2 + 1] = lsum;
  }
  __syncthreads();
  if (w < 4) {
    float mB = mML[(w * 64 + lane) * 2 + 0];
    float lB = mML[(w * 64 + lane) * 2 + 1];
    float mS = fmaxf(mq, mB);
    float fA = __expf(mq - mS), fB = __expf(mB - mS);
    float linv = 1.0f / (lsum * fA + lB * fB);
    float cAv = fA * linv, cBv = fB * linv;
    float cA[4], cB[4];
    #pragma unroll
    for (int r = 0; r < 4; ++r) {
      cA[r] = __shfl(cAv, lq * 4 + r);
      cB[r] = __shfl(cBv, lq * 4 + r);
    }
    int base = (w * 64 + lane) * 16;
    #pragma unroll
    for (int r = 0; r < 4; ++r) {
      int qr = i0 + qg * 16 + lq * 4 + r;
      #pragma unroll
      for (int n = 0; n < 4; ++n) {
        float v = oacc[n][r] * cA[r] + mO[base + n * 4 + r] * cB[r];
        size_t o = ((size_t)b * 1024 + qr) * 512 + h * 64 + n * 16 + l16;
        Oh[o] = f2bf(v);
      }
    }
  }
}

// ---------------------------------------------------------------------------
extern "C" void kernel_launch(void* const* d_in, const int* in_sizes, int n_in,
                              void* d_out, int out_size, void* d_ws, size_t ws_size,
                              hipStream_t stream) {
  const float* x     = (const float*)d_in[0];
  const float* q_w   = (const float*)d_in[1];
  const float* q_b   = (const float*)d_in[2];
  const float* k_w   = (const float*)d_in[3];
  const float* k_b   = (const float*)d_in[4];
  const float* v_w   = (const float*)d_in[5];
  const float* v_b   = (const float*)d_in[6];
  const float* o_w   = (const float*)d_in[7];
  const float* o_b   = (const float*)d_in[8];
  const float* dw_w  = (const float*)d_in[9];
  const float* dw_b  = (const float*)d_in[10];
  const float* off_w = (const float*)d_in[11];
  const float* btab  = (const float*)d_in[12];

  float* ws = (float*)d_ws;
  const size_t SZ = (size_t)4 * 1024 * 512;  // 2M elements
  float* samp = ws;                          // 65536 floats

  ushort* u = (ushort*)(samp + 65536);
  ushort* Xh    = u;               // 2M ushorts each
  ushort* Qb    = Xh + SZ;
  ushort* Kb    = Qb + SZ;
  ushort* Vb    = Kb + SZ;
  ushort* Ksb   = Vb + SZ;
  ushort* Vtr   = Ksb + SZ;
  ushort* Aoh   = Vtr + SZ;
  ushort* biasb = Aoh + SZ;        // 1M ushorts (2 MB)
  ushort* Wq    = biasb + 1048576; // 256K ushorts each
  ushort* Wk    = Wq + 262144;
  ushort* Wv    = Wk + 262144;
  ushort* Woh   = Wv + 262144;
  ushort* Wol   = Woh + 262144;

  stage1<<<4608, 256, 0, stream>>>(x, q_w, k_w, v_w, o_w, dw_w, dw_b, off_w,
                                   btab, Xh, Wq, Wk, Wv, Woh, Wol, samp, biasb);

  gemm_qkv<<<dim3(24, 32), 256, 0, stream>>>(Xh, Wq, Wk, Wv, q_b, k_b, v_b,
                                             Qb, Kb, Vb);

  grid_sample<<<dim3(16, 32), 256, 0, stream>>>(Kb, Vb, samp, Ksb, Vtr);

  attn_mfma<<<512, 512, 0, stream>>>(Qb, Ksb, Vtr, biasb, Aoh);

  gemm_o<<<dim3(8, 64), 256, 0, stream>>>(Aoh, Woh, Wol, o_b, (float*)d_out);
}